// Round 6
// baseline (288.245 us; speedup 1.0000x reference)
//
#include <hip/hip_runtime.h>
#include <hip/hip_cooperative_groups.h>
#include <math.h>

namespace cg = cooperative_groups;

#define BB 8
#define DD 128
#define KK 256
#define XYZ 32768
#define EPSV 1e-5f

// ws layout (float offsets)
#define WS_X    0                     // [B*32, 256] = 65536
#define WS_Y    65536
#define WS_Z    131072
#define WS_SM   196608                // [B*32, 4] partial (m0,l0,m1,l1) = 1024
#define WS_SHH  (WS_SM + 1024)        // ||Vh||^2
#define WS_LOG  (WS_SHH + 16)         // [B,256] logits accumulator = 2048

// Fused cooperative kernel: grid 256 x 256 threads, 1+ block/CU.
// Phase 1: projections (blocks 0..191, 4 rows each) + WS_LOG zero (192)
//          + ||Vh||^2 (193).
// Phase 2: per-(b,x) trilinear scores in registers + softmax (m,l) partials.
// Phase 3: finalize softmax across x, att out, contraction -> atomic logits.
// Phase 4: block 0 batchnorm.
__global__ void __launch_bounds__(256)
tan_fused_kernel(const float* x, const float* y, const float* z,
                 const float* Vx, const float* Vy, const float* Vz,
                 const float* gx, const float* gy, const float* gz,
                 const float* bx, const float* by, const float* bz,
                 const float* Vh, const float* gh, const float* bh,
                 const float* gamma, const float* beta,
                 float* ws, float* out) {
    cg::grid_group grid = cg::this_grid();
    __shared__ float smem[16384];   // ys[0:8192) zs[8192:16384); later e0/e1/as4
    __shared__ float lin[4 * DD];
    __shared__ float wred[4];
    __shared__ float smred[4][4];
    __shared__ float cons[4];

    int t = threadIdx.x;
    int bid = blockIdx.x;

    // ---------------- phase 1 ----------------
    if (bid < 192) {
        int which = bid >> 6;
        int r0 = (bid & 63) * 4;
        const float *in, *V, *g, *bias;
        float* outp;
        if (which == 0)      { in = x; V = Vx; g = gx; bias = bx; outp = ws + WS_X; }
        else if (which == 1) { in = y; V = Vy; g = gy; bias = by; outp = ws + WS_Y; }
        else                 { in = z; V = Vz; g = gz; bias = bz; outp = ws + WS_Z; }
        int f0 = t, f1 = t + 256;
        lin[f0] = in[(r0 + (f0 >> 7)) * DD + (f0 & 127)];
        lin[f1] = in[(r0 + (f1 >> 7)) * DD + (f1 & 127)];
        __syncthreads();
        const float4* v4 = (const float4*)(V + t * DD);
        const float4* l4 = (const float4*)lin;
        float a0 = 0.f, a1 = 0.f, a2 = 0.f, a3 = 0.f, ssp = 0.f;
#pragma unroll 8
        for (int d4 = 0; d4 < DD / 4; ++d4) {
            float4 a = v4[d4];
            ssp += a.x * a.x + a.y * a.y + a.z * a.z + a.w * a.w;
            float4 b0 = l4[d4];
            float4 b1 = l4[32 + d4];
            float4 b2 = l4[64 + d4];
            float4 b3 = l4[96 + d4];
            a0 += a.x * b0.x + a.y * b0.y + a.z * b0.z + a.w * b0.w;
            a1 += a.x * b1.x + a.y * b1.y + a.z * b1.z + a.w * b1.w;
            a2 += a.x * b2.x + a.y * b2.y + a.z * b2.z + a.w * b2.w;
            a3 += a.x * b3.x + a.y * b3.y + a.z * b3.z + a.w * b3.w;
        }
#pragma unroll
        for (int o = 32; o > 0; o >>= 1) ssp += __shfl_xor(ssp, o);
        if ((t & 63) == 0) wred[t >> 6] = ssp;
        __syncthreads();
        float ss = wred[0] + wred[1] + wred[2] + wred[3];
        float scale = g[0] * rsqrtf(ss);
        float bv = bias[t];
        outp[(r0 + 0) * KK + t] = fmaxf(a0 * scale + bv, 0.f);
        outp[(r0 + 1) * KK + t] = fmaxf(a1 * scale + bv, 0.f);
        outp[(r0 + 2) * KK + t] = fmaxf(a2 * scale + bv, 0.f);
        outp[(r0 + 3) * KK + t] = fmaxf(a3 * scale + bv, 0.f);
    } else if (bid == 192) {
        for (int i = t; i < 2048; i += 256) ws[WS_LOG + i] = 0.f;
    } else if (bid == 193) {
        if (t < 64) {
            float4 h1 = *(const float4*)(Vh + t * 8);
            float4 h2 = *(const float4*)(Vh + t * 8 + 4);
            float hs = h1.x * h1.x + h1.y * h1.y + h1.z * h1.z + h1.w * h1.w
                     + h2.x * h2.x + h2.y * h2.y + h2.z * h2.z + h2.w * h2.w;
#pragma unroll
            for (int o = 32; o > 0; o >>= 1) hs += __shfl_xor(hs, o);
            if (t == 0) ws[WS_SHH] = hs;
        }
    }
    __threadfence();
    grid.sync();

    // ---------------- phase 2: scores ----------------
    int bb = bid >> 5;
    int xx = bid & 31;
    const float* _xb = ws + WS_X + (bb * 32 + xx) * KK;
    const float* _yb = ws + WS_Y + bb * 8192;
    const float* _zb = ws + WS_Z + bb * 8192;
    float sh = gh[0] * rsqrtf(ws[WS_SHH]);
    float* ys = smem;
    float* zs = smem + 8192;

#pragma unroll
    for (int i = 0; i < 8; ++i) {
        int flat = i * 1024 + t * 4;
        int row = flat >> 8;
        int k = flat & 255;
        int gsw = (((k >> 2) ^ (row & 7)) << 2);
        *(float4*)(ys + row * 256 + gsw) = *(const float4*)(_yb + flat);
        *(float4*)(zs + row * 256 + gsw) = *(const float4*)(_zb + flat);
    }
    __syncthreads();

    int ty = t >> 4;
    int tz = t & 15;
    int y0 = ty, y1 = ty + 16;
    int z0 = tz, z1 = tz + 16;
    int ysw0 = (y0 & 7), ysw1 = (y1 & 7);
    int zsw0 = (z0 & 7), zsw1 = (z1 & 7);

    float a000 = 0.f, a001 = 0.f, a010 = 0.f, a011 = 0.f;
    float a100 = 0.f, a101 = 0.f, a110 = 0.f, a111 = 0.f;

#pragma unroll 4
    for (int kc = 0; kc < 256; kc += 4) {
        int g = kc >> 2;
        float4 xv  = *(const float4*)(_xb + kc);
        float4 vh0 = *(const float4*)(Vh + kc);
        float4 vh1 = *(const float4*)(Vh + KK + kc);
        float4 ya = *(const float4*)(ys + y0 * 256 + ((g ^ ysw0) << 2));
        float4 yb = *(const float4*)(ys + y1 * 256 + ((g ^ ysw1) << 2));
        float4 za = *(const float4*)(zs + z0 * 256 + ((g ^ zsw0) << 2));
        float4 zb = *(const float4*)(zs + z1 * 256 + ((g ^ zsw1) << 2));
#define TAN_STEP(c) { \
        float xs = sh * xv.c; \
        float w0 = xs * vh0.c, w1 = xs * vh1.c; \
        float t00 = w0 * ya.c, t01 = w0 * yb.c; \
        float t10 = w1 * ya.c, t11 = w1 * yb.c; \
        a000 = fmaf(t00, za.c, a000); a001 = fmaf(t00, zb.c, a001); \
        a010 = fmaf(t01, za.c, a010); a011 = fmaf(t01, zb.c, a011); \
        a100 = fmaf(t10, za.c, a100); a101 = fmaf(t10, zb.c, a101); \
        a110 = fmaf(t11, za.c, a110); a111 = fmaf(t11, zb.c, a111); }
        TAN_STEP(x) TAN_STEP(y) TAN_STEP(z) TAN_STEP(w)
#undef TAN_STEP
    }

    float b0 = bh[0], b1 = bh[1];
    a000 += b0; a001 += b0; a010 += b0; a011 += b0;
    a100 += b1; a101 += b1; a110 += b1; a111 += b1;

    // extract y/z columns (feature k=t) from LDS before smem is reused
    float yreg[32], zreg[32];
#pragma unroll
    for (int r = 0; r < 32; ++r) {
        int sw = ((((t >> 2) ^ (r & 7)) << 2) | (t & 3));
        yreg[r] = ys[r * 256 + sw];
        zreg[r] = zs[r * 256 + sw];
    }

    // per-(b,x) online softmax partials
    float m0 = fmaxf(fmaxf(a000, a001), fmaxf(a010, a011));
    float l0 = __expf(a000 - m0) + __expf(a001 - m0)
             + __expf(a010 - m0) + __expf(a011 - m0);
    float m1 = fmaxf(fmaxf(a100, a101), fmaxf(a110, a111));
    float l1 = __expf(a100 - m1) + __expf(a101 - m1)
             + __expf(a110 - m1) + __expf(a111 - m1);
#pragma unroll
    for (int o = 1; o < 64; o <<= 1) {
        float mo = __shfl_xor(m0, o), lo = __shfl_xor(l0, o);
        float nm = fmaxf(m0, mo);
        l0 = l0 * __expf(m0 - nm) + lo * __expf(mo - nm); m0 = nm;
        mo = __shfl_xor(m1, o); lo = __shfl_xor(l1, o);
        nm = fmaxf(m1, mo);
        l1 = l1 * __expf(m1 - nm) + lo * __expf(mo - nm); m1 = nm;
    }
    if ((t & 63) == 0) {
        int w = t >> 6;
        smred[w][0] = m0; smred[w][1] = l0;
        smred[w][2] = m1; smred[w][3] = l1;
    }
    __syncthreads();
    if (t == 0) {
        float M0 = smred[0][0], L0 = smred[0][1];
        float M1 = smred[0][2], L1 = smred[0][3];
#pragma unroll
        for (int w = 1; w < 4; ++w) {
            float nm = fmaxf(M0, smred[w][0]);
            L0 = L0 * __expf(M0 - nm) + smred[w][1] * __expf(smred[w][0] - nm);
            M0 = nm;
            nm = fmaxf(M1, smred[w][2]);
            L1 = L1 * __expf(M1 - nm) + smred[w][3] * __expf(smred[w][2] - nm);
            M1 = nm;
        }
        float* sm = ws + WS_SM + (bb * 32 + xx) * 4;
        sm[0] = M0; sm[1] = L0; sm[2] = M1; sm[3] = L1;
    }
    __threadfence();
    grid.sync();

    // ---------------- phase 3: finalize + att + logits ----------------
    if (t < 64) {
        const float* sm = ws + WS_SM + (bb * 32 + (t & 31)) * 4;
        float4 p = *(const float4*)sm;
        float fm0 = p.x, fl0 = p.y, fm1 = p.z, fl1 = p.w;
#pragma unroll
        for (int o = 1; o < 32; o <<= 1) {
            float mo = __shfl_xor(fm0, o), lo = __shfl_xor(fl0, o);
            float nm = fmaxf(fm0, mo);
            fl0 = fl0 * __expf(fm0 - nm) + lo * __expf(mo - nm); fm0 = nm;
            mo = __shfl_xor(fm1, o); lo = __shfl_xor(fl1, o);
            nm = fmaxf(fm1, mo);
            fl1 = fl1 * __expf(fm1 - nm) + lo * __expf(mo - nm); fm1 = nm;
        }
        if (t == 0) {
            cons[0] = fm0; cons[1] = 1.f / fl0;
            cons[2] = fm1; cons[3] = 1.f / fl1;
        }
    }
    __syncthreads();
    float M0 = cons[0], inv0 = cons[1], M1 = cons[2], inv1 = cons[3];

    // smem reuse: e0[1024] e1[1024] as4[1024]  (ys/zs fully consumed)
    float* e0p = smem;
    float* e1p = smem + 1024;
    float* as4 = smem + 2048;
    float e000 = __expf(a000 - M0) * inv0;
    float e001 = __expf(a001 - M0) * inv0;
    float e010 = __expf(a010 - M0) * inv0;
    float e011 = __expf(a011 - M0) * inv0;
    float e100 = __expf(a100 - M1) * inv1;
    float e101 = __expf(a101 - M1) * inv1;
    float e110 = __expf(a110 - M1) * inv1;
    float e111 = __expf(a111 - M1) * inv1;
    e0p[y0 * 32 + z0] = e000;  e0p[y0 * 32 + z1] = e001;
    e0p[y1 * 32 + z0] = e010;  e0p[y1 * 32 + z1] = e011;
    e1p[y0 * 32 + z0] = e100;  e1p[y0 * 32 + z1] = e101;
    e1p[y1 * 32 + z0] = e110;  e1p[y1 * 32 + z1] = e111;
    as4[y0 * 32 + z0] = e000 + e100;  as4[y0 * 32 + z1] = e001 + e101;
    as4[y1 * 32 + z0] = e010 + e110;  as4[y1 * 32 + z1] = e011 + e111;
    __syncthreads();

    // coalesced att writes (required output)
    float4* o0 = (float4*)(out + BB * KK + (bb * 2) * XYZ + xx * 1024);
    float4* o1 = o0 + XYZ / 4;
    o0[t] = ((const float4*)e0p)[t];
    o1[t] = ((const float4*)e1p)[t];

    // contraction: logit[k=t] partial for this (b,x)
    float acc = 0.f;
#pragma unroll 4
    for (int yy = 0; yy < 32; ++yy) {
        float s = 0.f;
        const float4* ar = (const float4*)(as4 + yy * 32);
#pragma unroll
        for (int j = 0; j < 8; ++j) {
            float4 a = ar[j];
            s += a.x * zreg[j * 4] + a.y * zreg[j * 4 + 1]
               + a.z * zreg[j * 4 + 2] + a.w * zreg[j * 4 + 3];
        }
        acc = fmaf(yreg[yy], s, acc);
    }
    float xv = ws[WS_X + (bb * 32 + xx) * 256 + t];
    atomicAdd(ws + WS_LOG + bb * 256 + t, xv * acc);
    __threadfence();
    grid.sync();

    // ---------------- phase 4: batchnorm (block 0) ----------------
    if (bid == 0) {
        int k = t;
        const float* lgp = ws + WS_LOG;
        float lg[BB];
#pragma unroll
        for (int b = 0; b < BB; ++b) lg[b] = lgp[b * 256 + k];
        float mean = 0.f;
#pragma unroll
        for (int b = 0; b < BB; ++b) mean += lg[b];
        mean *= 0.125f;
        float var = 0.f;
#pragma unroll
        for (int b = 0; b < BB; ++b) { float d = lg[b] - mean; var += d * d; }
        var *= 0.125f;
        float inv = rsqrtf(var + EPSV);
        float gm = gamma[k], bt = beta[k];
#pragma unroll
        for (int b = 0; b < BB; ++b)
            out[b * 256 + k] = (lg[b] - mean) * inv * gm + bt;
    }
}

extern "C" void kernel_launch(void* const* d_in, const int* in_sizes, int n_in,
                              void* d_out, int out_size, void* d_ws, size_t ws_size,
                              hipStream_t stream) {
    (void)in_sizes; (void)n_in; (void)out_size; (void)ws_size;
    const float* x     = (const float*)d_in[0];
    const float* y     = (const float*)d_in[1];
    const float* z     = (const float*)d_in[2];
    const float* Vx    = (const float*)d_in[3];
    const float* gx    = (const float*)d_in[4];
    const float* bx    = (const float*)d_in[5];
    const float* Vy    = (const float*)d_in[6];
    const float* gy    = (const float*)d_in[7];
    const float* by    = (const float*)d_in[8];
    const float* Vz    = (const float*)d_in[9];
    const float* gz    = (const float*)d_in[10];
    const float* bz    = (const float*)d_in[11];
    const float* Vh    = (const float*)d_in[12];
    const float* gh    = (const float*)d_in[13];
    const float* bh    = (const float*)d_in[14];
    const float* gamma = (const float*)d_in[15];
    const float* beta  = (const float*)d_in[16];
    float* ws  = (float*)d_ws;
    float* out = (float*)d_out;

    void* args[] = {
        (void*)&x, (void*)&y, (void*)&z,
        (void*)&Vx, (void*)&Vy, (void*)&Vz,
        (void*)&gx, (void*)&gy, (void*)&gz,
        (void*)&bx, (void*)&by, (void*)&bz,
        (void*)&Vh, (void*)&gh, (void*)&bh,
        (void*)&gamma, (void*)&beta,
        (void*)&ws, (void*)&out,
    };
    hipLaunchCooperativeKernel((void*)tan_fused_kernel, dim3(256), dim3(256),
                               args, 0, stream);
}

// Round 7
// 131.761 us; speedup vs baseline: 2.1876x; 2.1876x over previous
//
#include <hip/hip_runtime.h>
#include <math.h>

#define BB 8
#define DD 128
#define KK 256
#define XYZ 32768
#define EPSV 1e-5f

// ws layout (float offsets)
#define WS_X     0                     // [B*32, 256] = 65536
#define WS_Y     65536
#define WS_Z     131072
#define WS_RAW   196608                // [B,H,XYZ] = 524288
#define WS_SM    (WS_RAW + 524288)     // [B*32, 4] partial (m0,l0,m1,l1) = 1024
#define WS_LOG   (WS_SM + 1024)        // [B,256] logits accumulator = 2048
#define WS_TICK  (WS_LOG + 2048)       // 1 int ticket

// ---------------------------------------------------------------- projections
// grid 193: blocks 0..191: which = bid/64 (0:x 1:y 2:z), 4 rows each.
// block 192: zero WS_LOG + ticket (replaces hipMemsetAsync dispatch).
__global__ void __launch_bounds__(256)
tan_proj_kernel(const float* x, const float* y, const float* z,
                const float* Vx, const float* Vy, const float* Vz,
                const float* gx, const float* gy, const float* gz,
                const float* bx, const float* by, const float* bz,
                float* ws) {
    __shared__ float lin[4 * DD];
    __shared__ float wred[4];
    int bid = blockIdx.x;
    int t = threadIdx.x;
    if (bid == 192) {
        for (int i = t; i < 2048; i += 256) ws[WS_LOG + i] = 0.f;
        if (t == 0) ((int*)(ws + WS_TICK))[0] = 0;
        return;
    }
    int which = bid >> 6;
    int rgrp = bid & 63;
    int r0 = rgrp * 4;
    const float *in, *V, *g, *bias;
    float* outp;
    if (which == 0)      { in = x; V = Vx; g = gx; bias = bx; outp = ws + WS_X; }
    else if (which == 1) { in = y; V = Vy; g = gy; bias = by; outp = ws + WS_Y; }
    else                 { in = z; V = Vz; g = gz; bias = bz; outp = ws + WS_Z; }
    {
        int f0 = t, f1 = t + 256;
        lin[f0] = in[(r0 + (f0 >> 7)) * DD + (f0 & 127)];
        lin[f1] = in[(r0 + (f1 >> 7)) * DD + (f1 & 127)];
    }
    __syncthreads();
    const float4* v4 = (const float4*)(V + t * DD);
    const float4* l4 = (const float4*)lin;
    float a0 = 0.f, a1 = 0.f, a2 = 0.f, a3 = 0.f, ssp = 0.f;
#pragma unroll 8
    for (int d4 = 0; d4 < DD / 4; ++d4) {
        float4 a = v4[d4];
        ssp += a.x * a.x + a.y * a.y + a.z * a.z + a.w * a.w;
        float4 b0 = l4[d4];
        float4 b1 = l4[32 + d4];
        float4 b2 = l4[64 + d4];
        float4 b3 = l4[96 + d4];
        a0 += a.x * b0.x + a.y * b0.y + a.z * b0.z + a.w * b0.w;
        a1 += a.x * b1.x + a.y * b1.y + a.z * b1.z + a.w * b1.w;
        a2 += a.x * b2.x + a.y * b2.y + a.z * b2.z + a.w * b2.w;
        a3 += a.x * b3.x + a.y * b3.y + a.z * b3.z + a.w * b3.w;
    }
#pragma unroll
    for (int o = 32; o > 0; o >>= 1) ssp += __shfl_xor(ssp, o);
    if ((t & 63) == 0) wred[t >> 6] = ssp;
    __syncthreads();
    float ss = wred[0] + wred[1] + wred[2] + wred[3];
    float scale = g[0] * rsqrtf(ss);
    float bv = bias[t];
    outp[(r0 + 0) * KK + t] = fmaxf(a0 * scale + bv, 0.f);
    outp[(r0 + 1) * KK + t] = fmaxf(a1 * scale + bv, 0.f);
    outp[(r0 + 2) * KK + t] = fmaxf(a2 * scale + bv, 0.f);
    outp[(r0 + 3) * KK + t] = fmaxf(a3 * scale + bv, 0.f);
}

// ---------------------------------------------------------------- raw scores
// grid 256: one block per (b,x). Emits raw scores + per-(b,x) softmax partials.
__global__ void __launch_bounds__(256)
tan_score_kernel(const float* Vh, const float* gh, const float* bh, float* ws) {
    __shared__ float ys[32 * 256];
    __shared__ float zs[32 * 256];
    __shared__ float shh;
    __shared__ float smred[4][4];
    int t = threadIdx.x;
    int bb = blockIdx.x >> 5;
    int xx = blockIdx.x & 31;
    const float* _xb = ws + WS_X + (bb * 32 + xx) * KK;
    const float* _yb = ws + WS_Y + bb * 8192;
    const float* _zb = ws + WS_Z + bb * 8192;

    if (t < 64) {
        float4 h1 = *(const float4*)(Vh + t * 8);
        float4 h2 = *(const float4*)(Vh + t * 8 + 4);
        float hs = h1.x * h1.x + h1.y * h1.y + h1.z * h1.z + h1.w * h1.w
                 + h2.x * h2.x + h2.y * h2.y + h2.z * h2.z + h2.w * h2.w;
#pragma unroll
        for (int o = 32; o > 0; o >>= 1) hs += __shfl_xor(hs, o);
        if (t == 0) shh = hs;
    }

#pragma unroll
    for (int i = 0; i < 8; ++i) {
        int flat = i * 1024 + t * 4;
        int row = flat >> 8;
        int k = flat & 255;
        int gsw = (((k >> 2) ^ (row & 7)) << 2);
        *(float4*)(ys + row * 256 + gsw) = *(const float4*)(_yb + flat);
        *(float4*)(zs + row * 256 + gsw) = *(const float4*)(_zb + flat);
    }
    __syncthreads();
    float sh = gh[0] * rsqrtf(shh);

    int ty = t >> 4;
    int tz = t & 15;
    int y0 = ty, y1 = ty + 16;
    int z0 = tz, z1 = tz + 16;
    int ysw0 = (y0 & 7), ysw1 = (y1 & 7);
    int zsw0 = (z0 & 7), zsw1 = (z1 & 7);

    float a000 = 0.f, a001 = 0.f, a010 = 0.f, a011 = 0.f;
    float a100 = 0.f, a101 = 0.f, a110 = 0.f, a111 = 0.f;

#pragma unroll 4
    for (int kc = 0; kc < 256; kc += 4) {
        int g = kc >> 2;
        float4 xv  = *(const float4*)(_xb + kc);
        float4 vh0 = *(const float4*)(Vh + kc);
        float4 vh1 = *(const float4*)(Vh + KK + kc);
        float4 ya = *(const float4*)(ys + y0 * 256 + ((g ^ ysw0) << 2));
        float4 yb = *(const float4*)(ys + y1 * 256 + ((g ^ ysw1) << 2));
        float4 za = *(const float4*)(zs + z0 * 256 + ((g ^ zsw0) << 2));
        float4 zb = *(const float4*)(zs + z1 * 256 + ((g ^ zsw1) << 2));
#define TAN_STEP(c) { \
        float xs = sh * xv.c; \
        float w0 = xs * vh0.c, w1 = xs * vh1.c; \
        float t00 = w0 * ya.c, t01 = w0 * yb.c; \
        float t10 = w1 * ya.c, t11 = w1 * yb.c; \
        a000 = fmaf(t00, za.c, a000); a001 = fmaf(t00, zb.c, a001); \
        a010 = fmaf(t01, za.c, a010); a011 = fmaf(t01, zb.c, a011); \
        a100 = fmaf(t10, za.c, a100); a101 = fmaf(t10, zb.c, a101); \
        a110 = fmaf(t11, za.c, a110); a111 = fmaf(t11, zb.c, a111); }
        TAN_STEP(x) TAN_STEP(y) TAN_STEP(z) TAN_STEP(w)
#undef TAN_STEP
    }

    float b0 = bh[0], b1 = bh[1];
    a000 += b0; a001 += b0; a010 += b0; a011 += b0;
    a100 += b1; a101 += b1; a110 += b1; a111 += b1;
    float* r0 = ws + WS_RAW + (bb * 2 + 0) * XYZ + xx * 1024;
    float* r1 = r0 + XYZ;
    r0[y0 * 32 + z0] = a000;  r0[y0 * 32 + z1] = a001;
    r0[y1 * 32 + z0] = a010;  r0[y1 * 32 + z1] = a011;
    r1[y0 * 32 + z0] = a100;  r1[y0 * 32 + z1] = a101;
    r1[y1 * 32 + z0] = a110;  r1[y1 * 32 + z1] = a111;

    // per-(b,x) online softmax partials
    float m0 = fmaxf(fmaxf(a000, a001), fmaxf(a010, a011));
    float l0 = __expf(a000 - m0) + __expf(a001 - m0)
             + __expf(a010 - m0) + __expf(a011 - m0);
    float m1 = fmaxf(fmaxf(a100, a101), fmaxf(a110, a111));
    float l1 = __expf(a100 - m1) + __expf(a101 - m1)
             + __expf(a110 - m1) + __expf(a111 - m1);
#pragma unroll
    for (int o = 1; o < 64; o <<= 1) {
        float mo = __shfl_xor(m0, o), lo = __shfl_xor(l0, o);
        float nm = fmaxf(m0, mo);
        l0 = l0 * __expf(m0 - nm) + lo * __expf(mo - nm); m0 = nm;
        mo = __shfl_xor(m1, o); lo = __shfl_xor(l1, o);
        nm = fmaxf(m1, mo);
        l1 = l1 * __expf(m1 - nm) + lo * __expf(mo - nm); m1 = nm;
    }
    if ((t & 63) == 0) {
        int w = t >> 6;
        smred[w][0] = m0; smred[w][1] = l0;
        smred[w][2] = m1; smred[w][3] = l1;
    }
    __syncthreads();
    if (t == 0) {
        float M0 = smred[0][0], L0 = smred[0][1];
        float M1 = smred[0][2], L1 = smred[0][3];
#pragma unroll
        for (int w = 1; w < 4; ++w) {
            float nm = fmaxf(M0, smred[w][0]);
            L0 = L0 * __expf(M0 - nm) + smred[w][1] * __expf(smred[w][0] - nm);
            M0 = nm;
            nm = fmaxf(M1, smred[w][2]);
            L1 = L1 * __expf(M1 - nm) + smred[w][3] * __expf(smred[w][2] - nm);
            M1 = nm;
        }
        float* sm = ws + WS_SM + (bb * 32 + xx) * 4;
        sm[0] = M0; sm[1] = L0; sm[2] = M1; sm[3] = L1;
    }
}

// ------------------------ fused softmax-finalize + logits + (last-block) BN
// grid 256: b = bid>>5, x = bid&31; 256 threads (thread = k).
__global__ void __launch_bounds__(256)
tan_logits_kernel(float* ws, float* out,
                  const float* gamma, const float* beta) {
    __shared__ float as4[1024];
    __shared__ float cons[4];
    __shared__ int isLast;
    int b = blockIdx.x >> 5;
    int x = blockIdx.x & 31;
    int t = threadIdx.x;
    const float* _zb = ws + WS_Z + b * 8192;
    float zreg[32];
#pragma unroll
    for (int zi = 0; zi < 32; ++zi) zreg[zi] = _zb[zi * 256 + t];

    if (t < 64) {
        const float* sm = ws + WS_SM + (b * 32 + (t & 31)) * 4;
        float4 p = *(const float4*)sm;
        float m0 = p.x, l0 = p.y, m1 = p.z, l1 = p.w;
#pragma unroll
        for (int o = 1; o < 32; o <<= 1) {
            float mo = __shfl_xor(m0, o), lo = __shfl_xor(l0, o);
            float nm = fmaxf(m0, mo);
            l0 = l0 * __expf(m0 - nm) + lo * __expf(mo - nm); m0 = nm;
            mo = __shfl_xor(m1, o); lo = __shfl_xor(l1, o);
            nm = fmaxf(m1, mo);
            l1 = l1 * __expf(m1 - nm) + lo * __expf(mo - nm); m1 = nm;
        }
        if (t == 0) {
            cons[0] = m0; cons[1] = 1.f / l0;
            cons[2] = m1; cons[3] = 1.f / l1;
        }
    }
    __syncthreads();
    float M0 = cons[0], inv0 = cons[1], M1 = cons[2], inv1 = cons[3];
    const float* r0 = ws + WS_RAW + (b * 2) * XYZ + x * 1024;
    const float* r1 = r0 + XYZ;
    float* o0 = out + BB * KK + (b * 2) * XYZ + x * 1024;
    float* o1 = o0 + XYZ;
#pragma unroll
    for (int i = t; i < 1024; i += 256) {
        float a0 = __expf(r0[i] - M0) * inv0;
        float a1 = __expf(r1[i] - M1) * inv1;
        o0[i] = a0; o1[i] = a1;
        as4[i] = a0 + a1;
    }
    __syncthreads();

    const float* _yb = ws + WS_Y + b * 8192;
    float acc = 0.f;
#pragma unroll 4
    for (int y = 0; y < 32; ++y) {
        float s = 0.f;
        const float4* ar = (const float4*)(as4 + y * 32);
#pragma unroll
        for (int j = 0; j < 8; ++j) {
            float4 a = ar[j];
            s += a.x * zreg[j * 4] + a.y * zreg[j * 4 + 1]
               + a.z * zreg[j * 4 + 2] + a.w * zreg[j * 4 + 3];
        }
        acc = fmaf(_yb[y * 256 + t], s, acc);
    }
    float xv = ws[WS_X + (b * 32 + x) * 256 + t];
    atomicAdd(ws + WS_LOG + b * 256 + t, xv * acc);

    // ---- ticket: last block to finish does the batchnorm ----
    __threadfence();
    __syncthreads();
    if (t == 0)
        isLast = (atomicAdd((int*)(ws + WS_TICK), 1) == (int)gridDim.x - 1);
    __syncthreads();
    if (isLast) {
        __threadfence();
        int k = t;
        float lg[BB];
#pragma unroll
        for (int bb2 = 0; bb2 < BB; ++bb2)
            lg[bb2] = atomicAdd(ws + WS_LOG + bb2 * 256 + k, 0.0f);
        float mean = 0.f;
#pragma unroll
        for (int bb2 = 0; bb2 < BB; ++bb2) mean += lg[bb2];
        mean *= 0.125f;
        float var = 0.f;
#pragma unroll
        for (int bb2 = 0; bb2 < BB; ++bb2) { float d = lg[bb2] - mean; var += d * d; }
        var *= 0.125f;
        float inv = rsqrtf(var + EPSV);
        float gm = gamma[k], bt = beta[k];
#pragma unroll
        for (int bb2 = 0; bb2 < BB; ++bb2)
            out[bb2 * 256 + k] = (lg[bb2] - mean) * inv * gm + bt;
    }
}

extern "C" void kernel_launch(void* const* d_in, const int* in_sizes, int n_in,
                              void* d_out, int out_size, void* d_ws, size_t ws_size,
                              hipStream_t stream) {
    (void)in_sizes; (void)n_in; (void)out_size; (void)ws_size;
    const float* x     = (const float*)d_in[0];
    const float* y     = (const float*)d_in[1];
    const float* z     = (const float*)d_in[2];
    const float* Vx    = (const float*)d_in[3];
    const float* gx    = (const float*)d_in[4];
    const float* bx    = (const float*)d_in[5];
    const float* Vy    = (const float*)d_in[6];
    const float* gy    = (const float*)d_in[7];
    const float* by    = (const float*)d_in[8];
    const float* Vz    = (const float*)d_in[9];
    const float* gz    = (const float*)d_in[10];
    const float* bz    = (const float*)d_in[11];
    const float* Vh    = (const float*)d_in[12];
    const float* gh    = (const float*)d_in[13];
    const float* bh    = (const float*)d_in[14];
    const float* gamma = (const float*)d_in[15];
    const float* beta  = (const float*)d_in[16];
    float* ws  = (float*)d_ws;
    float* out = (float*)d_out;

    tan_proj_kernel<<<193, 256, 0, stream>>>(x, y, z, Vx, Vy, Vz,
                                             gx, gy, gz, bx, by, bz, ws);
    tan_score_kernel<<<256, 256, 0, stream>>>(Vh, gh, bh, ws);
    tan_logits_kernel<<<256, 256, 0, stream>>>(ws, out, gamma, beta);
}

// Round 8
// 120.615 us; speedup vs baseline: 2.3898x; 1.0924x over previous
//
#include <hip/hip_runtime.h>
#include <math.h>

#define BB 8
#define DD 128
#define KK 256
#define XYZ 32768
#define EPSV 1e-5f

// ws layout (float offsets)
#define WS_X     0                     // [B*32, 256] = 65536
#define WS_Y     65536
#define WS_Z     131072
#define WS_RAW   196608                // [B,H,XYZ] = 524288
#define WS_SM    (WS_RAW + 524288)     // [B*32, 4] partial (m0,l0,m1,l1) = 1024
#define WS_PART  (WS_SM + 1024)        // [B,32,256] logit partials = 65536

// ---------------------------------------------------------------- projections
// grid 192: which = bid/64 (0:x 1:y 2:z), 4 rows per block.
__global__ void __launch_bounds__(256)
tan_proj_kernel(const float* x, const float* y, const float* z,
                const float* Vx, const float* Vy, const float* Vz,
                const float* gx, const float* gy, const float* gz,
                const float* bx, const float* by, const float* bz,
                float* ws) {
    __shared__ float lin[4 * DD];
    __shared__ float wred[4];
    int bid = blockIdx.x;
    int t = threadIdx.x;
    int which = bid >> 6;
    int rgrp = bid & 63;
    int r0 = rgrp * 4;
    const float *in, *V, *g, *bias;
    float* outp;
    if (which == 0)      { in = x; V = Vx; g = gx; bias = bx; outp = ws + WS_X; }
    else if (which == 1) { in = y; V = Vy; g = gy; bias = by; outp = ws + WS_Y; }
    else                 { in = z; V = Vz; g = gz; bias = bz; outp = ws + WS_Z; }
    {
        int f0 = t, f1 = t + 256;
        lin[f0] = in[(r0 + (f0 >> 7)) * DD + (f0 & 127)];
        lin[f1] = in[(r0 + (f1 >> 7)) * DD + (f1 & 127)];
    }
    __syncthreads();
    const float4* v4 = (const float4*)(V + t * DD);
    const float4* l4 = (const float4*)lin;
    float a0 = 0.f, a1 = 0.f, a2 = 0.f, a3 = 0.f, ssp = 0.f;
#pragma unroll 8
    for (int d4 = 0; d4 < DD / 4; ++d4) {
        float4 a = v4[d4];
        ssp += a.x * a.x + a.y * a.y + a.z * a.z + a.w * a.w;
        float4 b0 = l4[d4];
        float4 b1 = l4[32 + d4];
        float4 b2 = l4[64 + d4];
        float4 b3 = l4[96 + d4];
        a0 += a.x * b0.x + a.y * b0.y + a.z * b0.z + a.w * b0.w;
        a1 += a.x * b1.x + a.y * b1.y + a.z * b1.z + a.w * b1.w;
        a2 += a.x * b2.x + a.y * b2.y + a.z * b2.z + a.w * b2.w;
        a3 += a.x * b3.x + a.y * b3.y + a.z * b3.z + a.w * b3.w;
    }
#pragma unroll
    for (int o = 32; o > 0; o >>= 1) ssp += __shfl_xor(ssp, o);
    if ((t & 63) == 0) wred[t >> 6] = ssp;
    __syncthreads();
    float ss = wred[0] + wred[1] + wred[2] + wred[3];
    float scale = g[0] * rsqrtf(ss);
    float bv = bias[t];
    outp[(r0 + 0) * KK + t] = fmaxf(a0 * scale + bv, 0.f);
    outp[(r0 + 1) * KK + t] = fmaxf(a1 * scale + bv, 0.f);
    outp[(r0 + 2) * KK + t] = fmaxf(a2 * scale + bv, 0.f);
    outp[(r0 + 3) * KK + t] = fmaxf(a3 * scale + bv, 0.f);
}

// ---------------------------------------------------------------- raw scores
// grid 256: one block per (b,x). Emits raw scores + per-(b,x) softmax partials.
__global__ void __launch_bounds__(256)
tan_score_kernel(const float* Vh, const float* gh, const float* bh, float* ws) {
    __shared__ float ys[32 * 256];
    __shared__ float zs[32 * 256];
    __shared__ float shh;
    __shared__ float smred[4][4];
    int t = threadIdx.x;
    int bb = blockIdx.x >> 5;
    int xx = blockIdx.x & 31;
    const float* _xb = ws + WS_X + (bb * 32 + xx) * KK;
    const float* _yb = ws + WS_Y + bb * 8192;
    const float* _zb = ws + WS_Z + bb * 8192;

    if (t < 64) {
        float4 h1 = *(const float4*)(Vh + t * 8);
        float4 h2 = *(const float4*)(Vh + t * 8 + 4);
        float hs = h1.x * h1.x + h1.y * h1.y + h1.z * h1.z + h1.w * h1.w
                 + h2.x * h2.x + h2.y * h2.y + h2.z * h2.z + h2.w * h2.w;
#pragma unroll
        for (int o = 32; o > 0; o >>= 1) hs += __shfl_xor(hs, o);
        if (t == 0) shh = hs;
    }

#pragma unroll
    for (int i = 0; i < 8; ++i) {
        int flat = i * 1024 + t * 4;
        int row = flat >> 8;
        int k = flat & 255;
        int gsw = (((k >> 2) ^ (row & 7)) << 2);
        *(float4*)(ys + row * 256 + gsw) = *(const float4*)(_yb + flat);
        *(float4*)(zs + row * 256 + gsw) = *(const float4*)(_zb + flat);
    }
    __syncthreads();
    float sh = gh[0] * rsqrtf(shh);

    int ty = t >> 4;
    int tz = t & 15;
    int y0 = ty, y1 = ty + 16;
    int z0 = tz, z1 = tz + 16;
    int ysw0 = (y0 & 7), ysw1 = (y1 & 7);
    int zsw0 = (z0 & 7), zsw1 = (z1 & 7);

    float a000 = 0.f, a001 = 0.f, a010 = 0.f, a011 = 0.f;
    float a100 = 0.f, a101 = 0.f, a110 = 0.f, a111 = 0.f;

#pragma unroll 4
    for (int kc = 0; kc < 256; kc += 4) {
        int g = kc >> 2;
        float4 xv  = *(const float4*)(_xb + kc);
        float4 vh0 = *(const float4*)(Vh + kc);
        float4 vh1 = *(const float4*)(Vh + KK + kc);
        float4 ya = *(const float4*)(ys + y0 * 256 + ((g ^ ysw0) << 2));
        float4 yb = *(const float4*)(ys + y1 * 256 + ((g ^ ysw1) << 2));
        float4 za = *(const float4*)(zs + z0 * 256 + ((g ^ zsw0) << 2));
        float4 zb = *(const float4*)(zs + z1 * 256 + ((g ^ zsw1) << 2));
#define TAN_STEP(c) { \
        float xs = sh * xv.c; \
        float w0 = xs * vh0.c, w1 = xs * vh1.c; \
        float t00 = w0 * ya.c, t01 = w0 * yb.c; \
        float t10 = w1 * ya.c, t11 = w1 * yb.c; \
        a000 = fmaf(t00, za.c, a000); a001 = fmaf(t00, zb.c, a001); \
        a010 = fmaf(t01, za.c, a010); a011 = fmaf(t01, zb.c, a011); \
        a100 = fmaf(t10, za.c, a100); a101 = fmaf(t10, zb.c, a101); \
        a110 = fmaf(t11, za.c, a110); a111 = fmaf(t11, zb.c, a111); }
        TAN_STEP(x) TAN_STEP(y) TAN_STEP(z) TAN_STEP(w)
#undef TAN_STEP
    }

    float b0 = bh[0], b1 = bh[1];
    a000 += b0; a001 += b0; a010 += b0; a011 += b0;
    a100 += b1; a101 += b1; a110 += b1; a111 += b1;
    float* r0 = ws + WS_RAW + (bb * 2 + 0) * XYZ + xx * 1024;
    float* r1 = r0 + XYZ;
    r0[y0 * 32 + z0] = a000;  r0[y0 * 32 + z1] = a001;
    r0[y1 * 32 + z0] = a010;  r0[y1 * 32 + z1] = a011;
    r1[y0 * 32 + z0] = a100;  r1[y0 * 32 + z1] = a101;
    r1[y1 * 32 + z0] = a110;  r1[y1 * 32 + z1] = a111;

    // per-(b,x) online softmax partials
    float m0 = fmaxf(fmaxf(a000, a001), fmaxf(a010, a011));
    float l0 = __expf(a000 - m0) + __expf(a001 - m0)
             + __expf(a010 - m0) + __expf(a011 - m0);
    float m1 = fmaxf(fmaxf(a100, a101), fmaxf(a110, a111));
    float l1 = __expf(a100 - m1) + __expf(a101 - m1)
             + __expf(a110 - m1) + __expf(a111 - m1);
#pragma unroll
    for (int o = 1; o < 64; o <<= 1) {
        float mo = __shfl_xor(m0, o), lo = __shfl_xor(l0, o);
        float nm = fmaxf(m0, mo);
        l0 = l0 * __expf(m0 - nm) + lo * __expf(mo - nm); m0 = nm;
        mo = __shfl_xor(m1, o); lo = __shfl_xor(l1, o);
        nm = fmaxf(m1, mo);
        l1 = l1 * __expf(m1 - nm) + lo * __expf(mo - nm); m1 = nm;
    }
    if ((t & 63) == 0) {
        int w = t >> 6;
        smred[w][0] = m0; smred[w][1] = l0;
        smred[w][2] = m1; smred[w][3] = l1;
    }
    __syncthreads();
    if (t == 0) {
        float M0 = smred[0][0], L0 = smred[0][1];
        float M1 = smred[0][2], L1 = smred[0][3];
#pragma unroll
        for (int w = 1; w < 4; ++w) {
            float nm = fmaxf(M0, smred[w][0]);
            L0 = L0 * __expf(M0 - nm) + smred[w][1] * __expf(smred[w][0] - nm);
            M0 = nm;
            nm = fmaxf(M1, smred[w][2]);
            L1 = L1 * __expf(M1 - nm) + smred[w][3] * __expf(smred[w][2] - nm);
            M1 = nm;
        }
        float* sm = ws + WS_SM + (bb * 32 + xx) * 4;
        sm[0] = M0; sm[1] = L0; sm[2] = M1; sm[3] = L1;
    }
}

// ------------------------ fused softmax-finalize + logits partials
// grid 256: b = bid>>5, x = bid&31; 256 threads (thread = k).
__global__ void __launch_bounds__(256)
tan_logits_kernel(float* ws, float* out) {
    __shared__ float as4[1024];
    __shared__ float cons[4];
    int b = blockIdx.x >> 5;
    int x = blockIdx.x & 31;
    int t = threadIdx.x;
    const float* _zb = ws + WS_Z + b * 8192;
    float zreg[32];
#pragma unroll
    for (int zi = 0; zi < 32; ++zi) zreg[zi] = _zb[zi * 256 + t];

    if (t < 64) {
        const float* sm = ws + WS_SM + (b * 32 + (t & 31)) * 4;
        float4 p = *(const float4*)sm;
        float m0 = p.x, l0 = p.y, m1 = p.z, l1 = p.w;
#pragma unroll
        for (int o = 1; o < 32; o <<= 1) {
            float mo = __shfl_xor(m0, o), lo = __shfl_xor(l0, o);
            float nm = fmaxf(m0, mo);
            l0 = l0 * __expf(m0 - nm) + lo * __expf(mo - nm); m0 = nm;
            mo = __shfl_xor(m1, o); lo = __shfl_xor(l1, o);
            nm = fmaxf(m1, mo);
            l1 = l1 * __expf(m1 - nm) + lo * __expf(mo - nm); m1 = nm;
        }
        if (t == 0) {
            cons[0] = m0; cons[1] = 1.f / l0;
            cons[2] = m1; cons[3] = 1.f / l1;
        }
    }
    __syncthreads();
    float M0 = cons[0], inv0 = cons[1], M1 = cons[2], inv1 = cons[3];
    const float* r0 = ws + WS_RAW + (b * 2) * XYZ + x * 1024;
    const float* r1 = r0 + XYZ;
    float* o0 = out + BB * KK + (b * 2) * XYZ + x * 1024;
    float* o1 = o0 + XYZ;
#pragma unroll
    for (int i = t; i < 1024; i += 256) {
        float a0 = __expf(r0[i] - M0) * inv0;
        float a1 = __expf(r1[i] - M1) * inv1;
        o0[i] = a0; o1[i] = a1;
        as4[i] = a0 + a1;
    }
    __syncthreads();

    const float* _yb = ws + WS_Y + b * 8192;
    float acc = 0.f;
#pragma unroll 4
    for (int y = 0; y < 32; ++y) {
        float s = 0.f;
        const float4* ar = (const float4*)(as4 + y * 32);
#pragma unroll
        for (int j = 0; j < 8; ++j) {
            float4 a = ar[j];
            s += a.x * zreg[j * 4] + a.y * zreg[j * 4 + 1]
               + a.z * zreg[j * 4 + 2] + a.w * zreg[j * 4 + 3];
        }
        acc = fmaf(_yb[y * 256 + t], s, acc);
    }
    float xv = ws[WS_X + (b * 32 + x) * 256 + t];
    ws[WS_PART + (b * 32 + x) * 256 + t] = xv * acc;
}

// ---------------------------------------------------------------- batchnorm
// 1 block, 1024 threads: tg = t>>8 sums 8 x-slices; LDS combine; tg 0 writes.
__global__ void __launch_bounds__(1024)
tan_bn_kernel(const float* ws, const float* gamma, const float* beta, float* out) {
    __shared__ float red[8192];
    int t = threadIdx.x;
    int tg = t >> 8;
    int k = t & 255;
    const float* part = ws + WS_PART;
    float lg[BB];
#pragma unroll
    for (int b = 0; b < BB; ++b) {
        float s = 0.f;
#pragma unroll
        for (int xi = 0; xi < 8; ++xi)
            s += part[(b * 32 + tg * 8 + xi) * 256 + k];
        red[tg * 2048 + b * 256 + k] = s;
    }
    __syncthreads();
    if (tg == 0) {
#pragma unroll
        for (int b = 0; b < BB; ++b)
            lg[b] = red[b * 256 + k] + red[2048 + b * 256 + k]
                  + red[4096 + b * 256 + k] + red[6144 + b * 256 + k];
        float mean = 0.f;
#pragma unroll
        for (int b = 0; b < BB; ++b) mean += lg[b];
        mean *= 0.125f;
        float var = 0.f;
#pragma unroll
        for (int b = 0; b < BB; ++b) { float d = lg[b] - mean; var += d * d; }
        var *= 0.125f;
        float inv = rsqrtf(var + EPSV);
        float gm = gamma[k], bt = beta[k];
#pragma unroll
        for (int b = 0; b < BB; ++b)
            out[b * 256 + k] = (lg[b] - mean) * inv * gm + bt;
    }
}

extern "C" void kernel_launch(void* const* d_in, const int* in_sizes, int n_in,
                              void* d_out, int out_size, void* d_ws, size_t ws_size,
                              hipStream_t stream) {
    (void)in_sizes; (void)n_in; (void)out_size; (void)ws_size;
    const float* x     = (const float*)d_in[0];
    const float* y     = (const float*)d_in[1];
    const float* z     = (const float*)d_in[2];
    const float* Vx    = (const float*)d_in[3];
    const float* gx    = (const float*)d_in[4];
    const float* bx    = (const float*)d_in[5];
    const float* Vy    = (const float*)d_in[6];
    const float* gy    = (const float*)d_in[7];
    const float* by    = (const float*)d_in[8];
    const float* Vz    = (const float*)d_in[9];
    const float* gz    = (const float*)d_in[10];
    const float* bz    = (const float*)d_in[11];
    const float* Vh    = (const float*)d_in[12];
    const float* gh    = (const float*)d_in[13];
    const float* bh    = (const float*)d_in[14];
    const float* gamma = (const float*)d_in[15];
    const float* beta  = (const float*)d_in[16];
    float* ws  = (float*)d_ws;
    float* out = (float*)d_out;

    tan_proj_kernel<<<192, 256, 0, stream>>>(x, y, z, Vx, Vy, Vz,
                                             gx, gy, gz, bx, by, bz, ws);
    tan_score_kernel<<<256, 256, 0, stream>>>(Vh, gh, bh, ws);
    tan_logits_kernel<<<256, 256, 0, stream>>>(ws, out);
    tan_bn_kernel<<<1, 1024, 0, stream>>>(ws, gamma, beta, out);
}